// Round 4
// baseline (419.105 us; speedup 1.0000x reference)
//
#include <hip/hip_runtime.h>

// Problem constants
#define DM 4096   // d_model
#define DSZ 64    // d_state
#define NE 1024   // num evicted
#define SQ 2048   // seq len
#define NB 4      // batch

typedef __attribute__((ext_vector_type(8))) short bf16x8;
typedef __attribute__((ext_vector_type(4))) float f32x4;

__device__ __forceinline__ unsigned f2bf(float f) {
  union { float f; unsigned u; } v; v.f = f;
  return (v.u + 0x7fffu + ((v.u >> 16) & 1u)) >> 16;  // RNE fp32->bf16
}
__device__ __forceinline__ unsigned pack2(float lo, float hi) {
  return f2bf(lo) | (f2bf(hi) << 16);
}

// Stage 16 fp32 (4x float4) as bf16 into LDS row [row][seg..seg+15]
__device__ __forceinline__ void stage16(unsigned short (*S)[72], int row, int seg,
                                        float4 a0, float4 a1, float4 a2, float4 a3) {
  uint4 p0 = { pack2(a0.x,a0.y), pack2(a0.z,a0.w), pack2(a1.x,a1.y), pack2(a1.z,a1.w) };
  uint4 p1 = { pack2(a2.x,a2.y), pack2(a2.z,a2.w), pack2(a3.x,a3.y), pack2(a3.z,a3.w) };
  *(uint4*)&S[row][seg]     = p0;
  *(uint4*)&S[row][seg + 8] = p1;
}

// 64x64 MFMA block over BK=64 staged tiles
__device__ __forceinline__ void mfma_64x64(const unsigned short (*A)[72], const unsigned short (*B)[72],
                                           int w, int m15, int quad, f32x4* acc) {
#pragma unroll
  for (int kk = 0; kk < 2; ++kk) {
    bf16x8 af = *(const bf16x8*)&A[w * 16 + m15][kk * 32 + quad * 8];
#pragma unroll
    for (int tn = 0; tn < 4; ++tn) {
      bf16x8 bfr = *(const bf16x8*)&B[tn * 16 + m15][kk * 32 + quad * 8];
      acc[tn] = __builtin_amdgcn_mfma_f32_16x16x32_bf16(af, bfr, acc[tn], 0, 0, 0);
    }
  }
}

// ---------------------------------------------------------------------------
// k_front: grid 1536.
//   blocks [0,512):    keys_part[ks][b][s][n] partial GEMM (ks=8 K-split of DM)
//   blocks [512,1024): summary[b][d] = mean_n evicted  (atomic partials)
//   blocks [1024,1536): q_part[ks][b][l][s] partial GEMM (ks=4) + gate logits
// All GEMM roles software-pipelined: prefetch chunk ch+1 during MFMA of ch.
// ---------------------------------------------------------------------------
__launch_bounds__(256)
__global__ void k_front(const float* __restrict__ ev, const float* __restrict__ Wk,
                        const float* __restrict__ cur, const float* __restrict__ Wq,
                        const float* __restrict__ gate_w,
                        float* __restrict__ keys_part, float* __restrict__ q_part,
                        float* __restrict__ summary, float* __restrict__ gate_acc) {
  __shared__ __align__(16) unsigned short As[64][72];
  __shared__ __align__(16) unsigned short Bs[64][72];
  __shared__ float gw[64];
  __shared__ float gred[256];
  const int bid = blockIdx.x;
  const int t = threadIdx.x;

  if (bid >= 512 && bid < 1024) {
    // ---- summary role: column mean of evicted over n ----
    const int bid2 = bid - 512;
    const int b = bid2 >> 7, rem = bid2 & 127;
    const int d0 = (rem >> 1) * 64, half = rem & 1;
    const int dl = t & 63, g = t >> 6;
    float acc = 0.f;
    const float* p = ev + ((size_t)(b * NE + half * 512 + g * 128)) * DM + d0 + dl;
    for (int i = 0; i < 128; ++i) { acc += *p; p += DM; }
    gred[t] = acc;
    __syncthreads();
    if (t < 64) {
      float tot = gred[t] + gred[t + 64] + gred[t + 128] + gred[t + 192];
      atomicAdd(&summary[b * DM + d0 + t], tot * (1.f / 1024.f));
    }
    return;
  }

  const int w = t >> 6, m15 = t & 15, quad = (t & 63) >> 4;
  const int rowS = t >> 2, seg = (t & 3) * 16;
  f32x4 acc[4];
#pragma unroll
  for (int i = 0; i < 4; ++i) acc[i] = (f32x4){0.f, 0.f, 0.f, 0.f};

  if (bid < 512) {
    // ---- keys GEMM role: 64(n) x 64(s) tile, K-slice 512, 8 chunks ----
    const int ks = bid & 7, mt = (bid >> 3) & 15, b = bid >> 7;
    const int n0 = mt * 64;
    const float* ap0 = ev + ((size_t)(b * NE + n0 + rowS)) * DM + ks * 512 + seg;
    const float* bp0 = Wk + (size_t)rowS * DM + ks * 512 + seg;
    float4 a0 = *(const float4*)(ap0),     a1 = *(const float4*)(ap0 + 4);
    float4 a2 = *(const float4*)(ap0 + 8), a3 = *(const float4*)(ap0 + 12);
    float4 b0 = *(const float4*)(bp0),     b1 = *(const float4*)(bp0 + 4);
    float4 b2 = *(const float4*)(bp0 + 8), b3 = *(const float4*)(bp0 + 12);
    for (int ch = 0; ch < 8; ++ch) {
      stage16(As, rowS, seg, a0, a1, a2, a3);
      stage16(Bs, rowS, seg, b0, b1, b2, b3);
      __syncthreads();
      const int off = (ch < 7 ? ch + 1 : 7) * 64;  // clamped prefetch
      a0 = *(const float4*)(ap0 + off);      a1 = *(const float4*)(ap0 + off + 4);
      a2 = *(const float4*)(ap0 + off + 8);  a3 = *(const float4*)(ap0 + off + 12);
      b0 = *(const float4*)(bp0 + off);      b1 = *(const float4*)(bp0 + off + 4);
      b2 = *(const float4*)(bp0 + off + 8);  b3 = *(const float4*)(bp0 + off + 12);
      mfma_64x64(As, Bs, w, m15, quad, acc);
      __syncthreads();
    }
    // D frag: row(n) = w*16+quad*4+r, col(s) = tn*16+m15
    const int n = n0 + w * 16 + quad * 4;
#pragma unroll
    for (int tn = 0; tn < 4; ++tn) {
      const int s = tn * 16 + m15;
      float4 v = { acc[tn][0], acc[tn][1], acc[tn][2], acc[tn][3] };
      *(float4*)&keys_part[(size_t)ks * (NB * DSZ * NE) + ((size_t)(b * DSZ + s)) * NE + n] = v;
    }
    return;
  }

  // ---- q GEMM role: 64(l) x 64(s) tile, K-slice 1024, 16 chunks, + gate ----
  const int bid2 = bid - 1024;
  const int ks = bid2 & 3, mt = (bid2 >> 2) & 31, b = bid2 >> 7;
  const int l0 = mt * 64;
  float gpart = 0.f;
  const float* ap0 = cur + ((size_t)(b * SQ + l0 + rowS)) * DM + ks * 1024 + seg;
  const float* bp0 = Wq + (size_t)rowS * DM + ks * 1024 + seg;
  const float* gp = gate_w + ks * 1024;
  float4 a0 = *(const float4*)(ap0),     a1 = *(const float4*)(ap0 + 4);
  float4 a2 = *(const float4*)(ap0 + 8), a3 = *(const float4*)(ap0 + 12);
  float4 b0 = *(const float4*)(bp0),     b1 = *(const float4*)(bp0 + 4);
  float4 b2 = *(const float4*)(bp0 + 8), b3 = *(const float4*)(bp0 + 12);
  for (int ch = 0; ch < 16; ++ch) {
    stage16(As, rowS, seg, a0, a1, a2, a3);
    stage16(Bs, rowS, seg, b0, b1, b2, b3);
    if (t < 16) *(float4*)&gw[t * 4] = *(const float4*)(gp + ch * 64 + t * 4);
    __syncthreads();
    {  // gate logit partial on current regs
      const float* g = &gw[seg];
      gpart += a0.x*g[0]  + a0.y*g[1]  + a0.z*g[2]  + a0.w*g[3]
             + a1.x*g[4]  + a1.y*g[5]  + a1.z*g[6]  + a1.w*g[7]
             + a2.x*g[8]  + a2.y*g[9]  + a2.z*g[10] + a2.w*g[11]
             + a3.x*g[12] + a3.y*g[13] + a3.z*g[14] + a3.w*g[15];
    }
    const int off = (ch < 15 ? ch + 1 : 15) * 64;  // clamped prefetch
    a0 = *(const float4*)(ap0 + off);      a1 = *(const float4*)(ap0 + off + 4);
    a2 = *(const float4*)(ap0 + off + 8);  a3 = *(const float4*)(ap0 + off + 12);
    b0 = *(const float4*)(bp0 + off);      b1 = *(const float4*)(bp0 + off + 4);
    b2 = *(const float4*)(bp0 + off + 8);  b3 = *(const float4*)(bp0 + off + 12);
    mfma_64x64(As, Bs, w, m15, quad, acc);
    __syncthreads();
  }
  const int lrow = l0 + w * 16 + quad * 4;
#pragma unroll
  for (int tn = 0; tn < 4; ++tn) {
#pragma unroll
    for (int r = 0; r < 4; ++r) {
      q_part[(size_t)ks * (NB * SQ * DSZ) + ((size_t)(b * SQ + lrow + r)) * DSZ + tn * 16 + m15] =
          acc[tn][r];
    }
  }
  gred[t] = gpart;
  __syncthreads();
  if (t < 64) {
    float tot = gred[4 * t] + gred[4 * t + 1] + gred[4 * t + 2] + gred[4 * t + 3];
    atomicAdd(&gate_acc[b * SQ + l0 + t], tot);
  }
}

// ---------------------------------------------------------------------------
// k_mid: grid 512.
//   blocks [0,256):   softmax over n of summed keys_part slabs -> ww_t bf16
//   blocks [256,512): beta[b][s] = sigmoid(summary·W_beta_w[s] + b)
// ---------------------------------------------------------------------------
__launch_bounds__(256)
__global__ void k_mid(const float* __restrict__ keys_part, const float* __restrict__ summary,
                      const float* __restrict__ Wbw, const float* __restrict__ Wbb,
                      float* __restrict__ beta, unsigned short* __restrict__ ww_t) {
  __shared__ float red[256];
  const int t = threadIdx.x;
  if (blockIdx.x < 256) {
    const int b = blockIdx.x >> 6, s = blockIdx.x & 63;
    const size_t base = ((size_t)(b * DSZ + s)) * NE + t * 4;
    float4 k = {0.f, 0.f, 0.f, 0.f};
#pragma unroll
    for (int sl = 0; sl < 8; ++sl) {
      float4 p = *(const float4*)&keys_part[(size_t)sl * (NB * DSZ * NE) + base];
      k.x += p.x; k.y += p.y; k.z += p.z; k.w += p.w;
    }
    float m = fmaxf(fmaxf(k.x, k.y), fmaxf(k.z, k.w));
    red[t] = m;
    __syncthreads();
    for (int off = 128; off > 0; off >>= 1) {
      if (t < off) red[t] = fmaxf(red[t], red[t + off]);
      __syncthreads();
    }
    const float M = red[0];
    __syncthreads();
    float4 e = { expf(k.x - M), expf(k.y - M), expf(k.z - M), expf(k.w - M) };
    red[t] = e.x + e.y + e.z + e.w;
    __syncthreads();
    for (int off = 128; off > 0; off >>= 1) {
      if (t < off) red[t] += red[t + off];
      __syncthreads();
    }
    const float inv = 1.f / red[0];
    ushort4 o = { (unsigned short)f2bf(e.x * inv), (unsigned short)f2bf(e.y * inv),
                  (unsigned short)f2bf(e.z * inv), (unsigned short)f2bf(e.w * inv) };
    *(ushort4*)&ww_t[((size_t)(b * DSZ + s)) * NE + t * 4] = o;
  } else {
    const int bx = blockIdx.x - 256;
    const int b = bx >> 6, s = bx & 63;
    const float* sp = summary + b * DM + t * 16;
    const float* wp = Wbw + (size_t)s * DM + t * 16;
    float acc = 0.f;
#pragma unroll
    for (int j = 0; j < 4; ++j) {
      float4 a  = *(const float4*)(sp + j * 4);
      float4 w4 = *(const float4*)(wp + j * 4);
      acc += a.x * w4.x + a.y * w4.y + a.z * w4.z + a.w * w4.w;
    }
    red[t] = acc;
    __syncthreads();
    for (int off = 128; off > 0; off >>= 1) {
      if (t < off) red[t] += red[t + off];
      __syncthreads();
    }
    if (t == 0) {
      float x = red[0] + Wbb[s];
      beta[b * DSZ + s] = 1.f / (1.f + expf(-x));
    }
  }
}

// ---------------------------------------------------------------------------
// k_update: grid 512 = B(4) x DT(128), d-tile 32 (2 blocks/CU).
// ns_t[b][d][s] bf16 = beta[b][s]*state[b][s][d] + sum_n ww[b][s][n]*ev[b][n][d]
// M=64(s) x N=32(d), BK=64(n), 16 chunks, prefetched.
// ---------------------------------------------------------------------------
__launch_bounds__(256)
__global__ void k_update(const float* __restrict__ ev, const float* __restrict__ state,
                         const float* __restrict__ beta, const unsigned short* __restrict__ ww_t,
                         unsigned short* __restrict__ ns_t) {
  __shared__ __align__(16) unsigned short Aw[64][72];  // [s][n]
  __shared__ __align__(16) unsigned short Bt[32][72];  // [d][n]
  const int bid = blockIdx.x;
  const int dt = bid & 127, b = bid >> 7;
  const int d0 = dt * 32;
  const int t = threadIdx.x;
  const int w = t >> 6, m15 = t & 15, quad = (t & 63) >> 4;
  const int rowS = t >> 2, seg = (t & 3) * 16;
  const int npair = (t & 31) * 2, dquad = (t >> 5) * 4;

  f32x4 acc[2];
  acc[0] = (f32x4){0.f, 0.f, 0.f, 0.f};
  acc[1] = (f32x4){0.f, 0.f, 0.f, 0.f};

  const unsigned short* wp0 = ww_t + ((size_t)(b * DSZ + rowS)) * NE + seg;
  const float* ep0 = ev + ((size_t)(b * NE + npair)) * DM + d0 + dquad;
  uint4 wa = *(const uint4*)(wp0), wb = *(const uint4*)(wp0 + 8);
  float4 r0 = *(const float4*)(ep0), r1 = *(const float4*)(ep0 + DM);

  for (int ch = 0; ch < 16; ++ch) {
    *(uint4*)&Aw[rowS][seg]     = wa;
    *(uint4*)&Aw[rowS][seg + 8] = wb;
    *(unsigned*)&Bt[dquad + 0][npair] = pack2(r0.x, r1.x);
    *(unsigned*)&Bt[dquad + 1][npair] = pack2(r0.y, r1.y);
    *(unsigned*)&Bt[dquad + 2][npair] = pack2(r0.z, r1.z);
    *(unsigned*)&Bt[dquad + 3][npair] = pack2(r0.w, r1.w);
    __syncthreads();
    const int nn = (ch < 15 ? ch + 1 : 15) * 64;  // clamped prefetch (n-rows)
    wa = *(const uint4*)(wp0 + nn);
    wb = *(const uint4*)(wp0 + nn + 8);
    const float* epn = ep0 + (size_t)nn * DM;
    r0 = *(const float4*)(epn);
    r1 = *(const float4*)(epn + DM);
#pragma unroll
    for (int kk = 0; kk < 2; ++kk) {
      bf16x8 af = *(const bf16x8*)&Aw[w * 16 + m15][kk * 32 + quad * 8];
#pragma unroll
      for (int tn = 0; tn < 2; ++tn) {
        bf16x8 bfr = *(const bf16x8*)&Bt[tn * 16 + m15][kk * 32 + quad * 8];
        acc[tn] = __builtin_amdgcn_mfma_f32_16x16x32_bf16(af, bfr, acc[tn], 0, 0, 0);
      }
    }
    __syncthreads();
  }
  const int sbase = w * 16 + quad * 4;
#pragma unroll
  for (int tn = 0; tn < 2; ++tn) {
    const int d = d0 + tn * 16 + m15;
    float v[4];
#pragma unroll
    for (int r = 0; r < 4; ++r) {
      const int s = sbase + r;
      v[r] = beta[b * DSZ + s] * state[((size_t)(b * DSZ + s)) * DM + d] + acc[tn][r];
    }
    ushort4 o = { (unsigned short)f2bf(v[0]), (unsigned short)f2bf(v[1]),
                  (unsigned short)f2bf(v[2]), (unsigned short)f2bf(v[3]) };
    *(ushort4*)&ns_t[((size_t)(b * DM + d)) * DSZ + sbase] = o;
  }
}

// ---------------------------------------------------------------------------
// k_out: grid 8192 = B(4) x LT(32) x DT(64). Fused q-slab sum (fp32) + pack +
// MFMA against ns_t + gate. No LDS.
// ---------------------------------------------------------------------------
__launch_bounds__(256)
__global__ void k_out(const float* __restrict__ q_part, const unsigned short* __restrict__ ns_t,
                      const float* __restrict__ gate_acc, const float* __restrict__ gate_b,
                      float* __restrict__ out) {
  const int bid = blockIdx.x;
  const int dt = bid & 63, lt = (bid >> 6) & 31, b = bid >> 11;
  const int d0 = dt * 64, l0 = lt * 64;
  const int t = threadIdx.x;
  const int w = t >> 6, m15 = t & 15, quad = (t & 63) >> 4;
  const int la = l0 + w * 16 + m15;
  const int SL = NB * SQ * DSZ;
  f32x4 acc[4];
#pragma unroll
  for (int i = 0; i < 4; ++i) acc[i] = (f32x4){0.f, 0.f, 0.f, 0.f};
#pragma unroll
  for (int kk = 0; kk < 2; ++kk) {
    const size_t qi = ((size_t)(b * SQ + la)) * DSZ + kk * 32 + quad * 8;
    float4 s0 = *(const float4*)&q_part[qi];
    float4 s1 = *(const float4*)&q_part[qi + 4];
#pragma unroll
    for (int sl = 1; sl < 4; ++sl) {
      float4 u0 = *(const float4*)&q_part[(size_t)sl * SL + qi];
      float4 u1 = *(const float4*)&q_part[(size_t)sl * SL + qi + 4];
      s0.x += u0.x; s0.y += u0.y; s0.z += u0.z; s0.w += u0.w;
      s1.x += u1.x; s1.y += u1.y; s1.z += u1.z; s1.w += u1.w;
    }
    union { bf16x8 v; unsigned u[4]; } af;
    af.u[0] = pack2(s0.x, s0.y); af.u[1] = pack2(s0.z, s0.w);
    af.u[2] = pack2(s1.x, s1.y); af.u[3] = pack2(s1.z, s1.w);
#pragma unroll
    for (int tn = 0; tn < 4; ++tn) {
      const int d = d0 + tn * 16 + m15;
      bf16x8 bfr = *(const bf16x8*)&ns_t[((size_t)(b * DM + d)) * DSZ + kk * 32 + quad * 8];
      acc[tn] = __builtin_amdgcn_mfma_f32_16x16x32_bf16(af.v, bfr, acc[tn], 0, 0, 0);
    }
  }
  const float gb = gate_b[0];
  const int lbase = l0 + w * 16 + quad * 4;
  float g[4];
#pragma unroll
  for (int r = 0; r < 4; ++r)
    g[r] = 1.f / (1.f + expf(-(gate_acc[b * SQ + lbase + r] + gb)));
#pragma unroll
  for (int tn = 0; tn < 4; ++tn) {
    const int d = d0 + tn * 16 + m15;
#pragma unroll
    for (int r = 0; r < 4; ++r)
      out[((size_t)(b * SQ + lbase + r)) * DM + d] = g[r] * acc[tn][r];
  }
}

// ---------------------------------------------------------------------------
extern "C" void kernel_launch(void* const* d_in, const int* in_sizes, int n_in,
                              void* d_out, int out_size, void* d_ws, size_t ws_size,
                              hipStream_t stream) {
  const float* state   = (const float*)d_in[0];
  const float* evicted = (const float*)d_in[1];
  const float* current = (const float*)d_in[2];
  const float* Wkey    = (const float*)d_in[3];
  const float* Wbw     = (const float*)d_in[4];
  const float* Wbb     = (const float*)d_in[5];
  const float* Wq      = (const float*)d_in[6];
  const float* gate_w  = (const float*)d_in[7];
  const float* gate_b  = (const float*)d_in[8];
  float* out = (float*)d_out;

  // workspace layout (~18.7 MB)
  float* f = (float*)d_ws;
  float* keys_part = f;                              // 8 * 262144 f  (8 MB)
  float* q_part    = keys_part + 8 * 262144;         // 4 * 524288 f  (8 MB)
  float* summary   = q_part + 4 * 524288;            // 16384 f
  float* gate_acc  = summary + 16384;                // 8192 f
  float* beta      = gate_acc + 8192;                // 256 f
  unsigned short* ww_t = (unsigned short*)(beta + 256);  // 262144 us (512 KB)
  unsigned short* ns_t = ww_t + 262144;                  // 1048576 us (2 MB)

  hipMemsetAsync(summary, 0, (16384 + 8192) * sizeof(float), stream);

  k_front <<<1536, 256, 0, stream>>>(evicted, Wkey, current, Wq, gate_w,
                                     keys_part, q_part, summary, gate_acc);
  k_mid   <<<512,  256, 0, stream>>>(keys_part, summary, Wbw, Wbb, beta, ww_t);
  k_update<<<512,  256, 0, stream>>>(evicted, state, beta, ww_t, ns_t);
  k_out   <<<8192, 256, 0, stream>>>(q_part, ns_t, gate_acc, gate_b, out);
}